// Round 1
// baseline (602.813 us; speedup 1.0000x reference)
//
#include <hip/hip_runtime.h>
#include <math.h>

#define B_  64
#define N_  325
#define T_  24
#define F_  64
#define H_  64
#define E_  2600
#define G_  (B_ * T_)
#define BLK 512
#define CHUNK 128
#define XPAD 68   // x_s row stride in floats (272 B, 16B-aligned, not a multiple of 128B)

// ---------------- K0a: per-dst counts -> exclusive offsets ----------------
__global__ __launch_bounds__(512) void k_offsets(const int* __restrict__ ei,
                                                 int* __restrict__ csr_off) {
  __shared__ int cnt[N_];
  const int tid = threadIdx.x;
  for (int i = tid; i < N_; i += BLK) cnt[i] = 0;
  __syncthreads();
  for (int e = tid; e < E_; e += BLK) atomicAdd(&cnt[ei[E_ + e]], 1);
  __syncthreads();
  if (tid <= N_) {
    int off = 0;
    for (int m = 0; m < N_; ++m) off += (m < tid) ? cnt[m] : 0;  // uniform m -> LDS broadcast
    csr_off[tid] = off;
  }
}

// ---------------- K0b: stable scatter of src ids by dst (deterministic) ----------------
__global__ __launch_bounds__(64) void k_scatter(const int* __restrict__ ei,
                                                const int* __restrict__ csr_off,
                                                int* __restrict__ csr_src) {
  __shared__ int dsts[E_];
  const int tid = threadIdx.x;
  for (int i = tid; i < E_; i += 64) dsts[i] = ei[E_ + i];
  __syncthreads();
  const int e = blockIdx.x * 64 + tid;
  if (e >= E_) return;
  const int myd = dsts[e];
  int rank = 0;
#pragma unroll 4
  for (int k = 0; k < e; ++k) rank += (dsts[k] == myd) ? 1 : 0;
  csr_src[csr_off[myd] + rank] = ei[e];  // src id, stable original-edge order
}

// ---------------- main fused kernel: one block per graph ----------------
__global__ __launch_bounds__(512, 1) void k_gat(
    const float* __restrict__ x, const int* __restrict__ csr_off_g,
    const int* __restrict__ csr_src_g, const float* __restrict__ W,
    const float* __restrict__ att_src, const float* __restrict__ att_dst,
    const float* __restrict__ bias, float* __restrict__ out) {
  __shared__ float h_s[N_][H_];                     // 83200 B, lane-contiguous access only
  __shared__ __align__(16) float x_s[CHUNK][XPAD];  // 34816 B
  __shared__ float alpha_s[E_];                     // 10400 B (unnormalized exp)
  __shared__ int   csrc_s[E_];                      // 10400 B
  __shared__ int   coff_s[N_ + 1];                  //  1304 B
  __shared__ float as_s[N_], ad_s[N_];              //  2600 B    total ~142.7 KB

  const int g    = blockIdx.x;      // graph id = b*T + t
  const int bb   = g / T_;
  const int tt   = g % T_;
  const int tid  = threadIdx.x;
  const int lane = tid & 63;        // = output channel h
  const int wv   = tid >> 6;        // wave 0..7

  // stage CSR
  for (int i = tid; i < E_; i += BLK) csrc_s[i] = csr_src_g[i];
  for (int i = tid; i <= N_; i += BLK) coff_s[i] = csr_off_g[i];

  // per-lane W row (lane = h channel) in registers; L1/L2 resident, 16 KB
  float wreg[F_];
  {
    const float4* w4 = (const float4*)(W + lane * F_);
#pragma unroll
    for (int i = 0; i < 16; ++i) {
      float4 v = w4[i];
      wreg[4 * i + 0] = v.x; wreg[4 * i + 1] = v.y;
      wreg[4 * i + 2] = v.z; wreg[4 * i + 3] = v.w;
    }
  }
  const float atts_r = att_src[lane];
  const float attd_r = att_dst[lane];
  const float bias_r = bias[lane];

  // ---------- Phase 1: h = x @ W^T, a_s = h.att_src, a_d = h.att_dst ----------
  // x[b][n][t][f] : row base for node n is xg + n*T_*F_
  const float* xg = x + ((size_t)bb * N_ * T_ + tt) * F_;
  for (int n0 = 0; n0 < N_; n0 += CHUNK) {
    const int C = (N_ - n0 < CHUNK) ? (N_ - n0) : CHUNK;
    __syncthreads();  // previous chunk's GEMM done before overwriting x_s
    // stage x chunk: 16 float4 per row, 16 consecutive lanes cover one 256B row
    for (int i = tid; i < C * 16; i += BLK) {
      const int r = i >> 4, f4 = i & 15;
      float4 v = *(const float4*)(xg + (size_t)(n0 + r) * T_ * F_ + f4 * 4);
      *(float4*)(&x_s[r][f4 * 4]) = v;
    }
    __syncthreads();
    // wave-per-row GEMM: lane=h, x broadcast from LDS (b128), W in regs
    for (int r = wv; r < C; r += 8) {
      const float4* xr4 = (const float4*)(&x_s[r][0]);
      float a0 = 0.f, a1 = 0.f, a2 = 0.f, a3 = 0.f;
#pragma unroll
      for (int i = 0; i < 16; ++i) {
        float4 v = xr4[i];
        a0 += v.x * wreg[4 * i + 0];
        a1 += v.y * wreg[4 * i + 1];
        a2 += v.z * wreg[4 * i + 2];
        a3 += v.w * wreg[4 * i + 3];
      }
      const float acc = (a0 + a1) + (a2 + a3);
      h_s[n0 + r][lane] = acc;                    // consecutive lanes -> consecutive banks
      float asv = acc * atts_r, adv = acc * attd_r;
#pragma unroll
      for (int m = 1; m < 64; m <<= 1) {
        asv += __shfl_xor(asv, m, 64);
        adv += __shfl_xor(adv, m, 64);
      }
      if (lane == 0) { as_s[n0 + r] = asv; ad_s[n0 + r] = adv; }
    }
  }
  __syncthreads();

  // ---------- Phase 2: per-dst segment softmax + aggregation + GELU ----------
  for (int n = wv; n < N_; n += 8) {
    const int beg = coff_s[n], end = coff_s[n + 1];
    float v;
    if (end > beg) {
      const float adn = ad_s[n];
      // pass 1: segment max (lanes parallel over edges)
      float mx = -1e30f;
      for (int p = beg + lane; p < end; p += 64) {
        float e = as_s[csrc_s[p]] + adn;
        e = fmaxf(e, 0.2f * e);                   // leaky_relu
        mx = fmaxf(mx, e);
      }
#pragma unroll
      for (int m = 1; m < 64; m <<= 1) mx = fmaxf(mx, __shfl_xor(mx, m, 64));
      // pass 2: exp + denominator
      float den = 0.f;
      for (int p = beg + lane; p < end; p += 64) {
        float e = as_s[csrc_s[p]] + adn;
        e = fmaxf(e, 0.2f * e);
        float ex = __expf(e - mx);
        alpha_s[p] = ex;                          // unnormalized
        den += ex;
      }
#pragma unroll
      for (int m = 1; m < 64; m <<= 1) den += __shfl_xor(den, m, 64);
      // make this wave's alpha_s writes visible to all its lanes
      asm volatile("s_waitcnt lgkmcnt(0)" ::: "memory");
      // pass 3: acc[h] = sum_e ex_e * h[src_e][h]   (lane = h)
      float acc = 0.f;
      for (int p = beg; p < end; ++p) {
        const float a = alpha_s[p];               // broadcast
        const int   s = csrc_s[p];                // broadcast
        acc += a * h_s[s][lane];                  // conflict-free
      }
      v = acc / den + bias_r;
    } else {
      v = bias_r;                                 // empty segment: segment_sum = 0
    }
    const float gel = 0.5f * v * (1.f + erff(v * 0.70710678118f));
    out[((size_t)g * N_ + n) * H_ + lane] = gel;  // flat [g][n][h] == view(B,T,N,H)
  }
}

extern "C" void kernel_launch(void* const* d_in, const int* in_sizes, int n_in,
                              void* d_out, int out_size, void* d_ws, size_t ws_size,
                              hipStream_t stream) {
  (void)in_sizes; (void)n_in; (void)out_size; (void)ws_size;
  const float* x       = (const float*)d_in[0];
  const int*   ei      = (const int*)d_in[1];
  const float* W       = (const float*)d_in[2];
  const float* att_src = (const float*)d_in[3];
  const float* att_dst = (const float*)d_in[4];
  const float* bias    = (const float*)d_in[5];
  float* out = (float*)d_out;
  int* csr_off = (int*)d_ws;              // N_+1 ints
  int* csr_src = csr_off + (N_ + 1);      // E_ ints

  k_offsets<<<1, BLK, 0, stream>>>(ei, csr_off);
  k_scatter<<<(E_ + 63) / 64, 64, 0, stream>>>(ei, csr_off, csr_src);
  k_gat<<<G_, BLK, 0, stream>>>(x, csr_off, csr_src, W, att_src, att_dst, bias, out);
}